// Round 4
// baseline (29.308 us; speedup 1.0000x reference)
//
#include <hip/hip_runtime.h>

#define NGT 64
#define NUM_CLASSES_F 80.0f
#define INF_F 100000000.0f
#define RADIUS_F 1.5f

__global__ __launch_bounds__(256) void fcos_match_kernel(
    const float* __restrict__ locations,      // (L,2)
    const float* __restrict__ strides_per_loc,// (L,)
    const float* __restrict__ soi,            // (L,2)
    const float* __restrict__ anchors,        // (L,4)
    const float* __restrict__ gt_boxes,       // (B,G,4)
    const int*   __restrict__ gt_classes,     // (B,G)
    float* __restrict__ out,                  // cls (B*L) | reg (B*L*4) | deltas (B*L*4)
    int L, int B)
{
    const int b = blockIdx.y;

    // AoS box table: sb[2j] = {x1,y1,x2,y2}, sb[2j+1] = {ccx,ccy,area,clsf}
    __shared__ float4 sb[NGT * 2];
    if (threadIdx.x < NGT) {
        const int j = threadIdx.x;
        const float4 bx = reinterpret_cast<const float4*>(gt_boxes)[b * NGT + j];
        sb[2 * j]     = bx;
        sb[2 * j + 1] = make_float4((bx.x + bx.z) * 0.5f,
                                    (bx.y + bx.w) * 0.5f,
                                    (bx.z - bx.x) * (bx.w - bx.y),
                                    (float)gt_classes[b * NGT + j]);
    }
    __syncthreads();

    // Two locations per thread: i and i+Lh (both streams coalesced).
    const int Lh = (L + 1) >> 1;
    const int t0 = blockIdx.x * blockDim.x + threadIdx.x;
    const bool a0 = t0 < Lh;
    const bool a1 = t0 + Lh < L;
    const int i0 = a0 ? t0 : 0;
    const int i1 = a1 ? (t0 + Lh) : 0;

    const float2 xy0 = reinterpret_cast<const float2*>(locations)[i0];
    const float2 xy1 = reinterpret_cast<const float2*>(locations)[i1];
    const float rad0 = strides_per_loc[i0] * RADIUS_F;
    const float rad1 = strides_per_loc[i1] * RADIUS_F;
    const float2 sh0 = reinterpret_cast<const float2*>(soi)[i0];
    const float2 sh1 = reinterpret_cast<const float2*>(soi)[i1];

    float minv0 = INF_F, minv1 = INF_F;
    int   ind0 = 0, ind1 = 0;

    #pragma unroll
    for (int j = 0; j < NGT; ++j) {
        const float4 bb = sb[2 * j];       // broadcast (same addr across wave)
        const float4 bd = sb[2 * j + 1];

        // ---- loc 0 ----
        {
            const float l = xy0.x - bb.x, t = xy0.y - bb.y;
            const float r = bb.z - xy0.x, d = bb.w - xy0.y;
            const float mx = fmaxf(fmaxf(fmaxf(l, t), r), d);     // max3+max
            const float mn = fminf(fminf(fminf(l, t), r), d);     // min3+min
            const float cx = rad0 - fabsf(xy0.x - bd.x);          // abs = free modifier
            const float cy = rad0 - fabsf(xy0.y - bd.y);
            const float cmin = fminf(fminf(mn, cx), cy);          // min3
            const float g = fminf(mx - sh0.x, sh0.y - mx);
            const float v = ((cmin > 0.0f) && (g >= 0.0f)) ? bd.z : INF_F;
            if (v < minv0) { minv0 = v; ind0 = j; }
        }
        // ---- loc 1 ----
        {
            const float l = xy1.x - bb.x, t = xy1.y - bb.y;
            const float r = bb.z - xy1.x, d = bb.w - xy1.y;
            const float mx = fmaxf(fmaxf(fmaxf(l, t), r), d);
            const float mn = fminf(fminf(fminf(l, t), r), d);
            const float cx = rad1 - fabsf(xy1.x - bd.x);
            const float cy = rad1 - fabsf(xy1.y - bd.y);
            const float cmin = fminf(fminf(mn, cx), cy);
            const float g = fminf(mx - sh1.x, sh1.y - mx);
            const float v = ((cmin > 0.0f) && (g >= 0.0f)) ? bd.z : INF_F;
            if (v < minv1) { minv1 = v; ind1 = j; }
        }
    }

    // ---------------- epilogue ----------------
    #pragma unroll
    for (int s = 0; s < 2; ++s) {
        const bool  act  = s ? a1 : a0;
        if (!act) continue;
        const int   i    = s ? i1 : i0;
        const float x    = s ? xy1.x : xy0.x;
        const float y    = s ? xy1.y : xy0.y;
        const float minv = s ? minv1 : minv0;
        const int   ind  = s ? ind1 : ind0;

        const float4 mb = sb[2 * ind];       // divergent LDS gather (tiny)
        const float4 md = sb[2 * ind + 1];

        out[(size_t)b * L + i] = (minv == INF_F) ? NUM_CLASSES_F : md.w;

        const size_t o4 = (size_t)b * L + i;
        float4* reg4 = reinterpret_cast<float4*>(out + (size_t)B * L) + o4;
        *reg4 = make_float4(x - mb.x, y - mb.y, mb.z - x, mb.w - y);

        const float4 an = reinterpret_cast<const float4*>(anchors)[i];
        const float aw  = an.z - an.x;
        const float ah  = an.w - an.y;
        const float acx = an.x + 0.5f * aw;
        const float acy = an.y + 0.5f * ah;
        const float gw  = mb.z - mb.x;
        const float gh  = mb.w - mb.y;
        const float gcx = mb.x + 0.5f * gw;
        const float gcy = mb.y + 0.5f * gh;

        float4* del4 = reinterpret_cast<float4*>(out + (size_t)B * L * 5) + o4;
        *del4 = make_float4((gcx - acx) / aw, (gcy - acy) / ah,
                            logf(gw / aw), logf(gh / ah));
    }
}

extern "C" void kernel_launch(void* const* d_in, const int* in_sizes, int n_in,
                              void* d_out, int out_size, void* d_ws, size_t ws_size,
                              hipStream_t stream) {
    const float* locations = (const float*)d_in[0];
    const float* strides   = (const float*)d_in[1];
    const float* soi       = (const float*)d_in[2];
    const float* anchors   = (const float*)d_in[3];
    const float* gt_boxes  = (const float*)d_in[4];
    const int*   gt_cls    = (const int*)d_in[5];
    float* out = (float*)d_out;

    const int L = in_sizes[1];            // strides_per_loc has L elements
    const int B = in_sizes[5] / NGT;      // gt_classes has B*G elements

    const int Lh = (L + 1) >> 1;
    dim3 grid((Lh + 255) / 256, B);
    fcos_match_kernel<<<grid, dim3(256), 0, stream>>>(locations, strides, soi, anchors,
                                                      gt_boxes, gt_cls, out, L, B);
}

// Round 5
// 14.354 us; speedup vs baseline: 2.0417x; 2.0417x over previous
//
#include <hip/hip_runtime.h>

#define NGT 64
#define NUM_CLASSES_F 80.0f
#define INF_F 100000000.0f
#define RADIUS_F 1.5f

__global__ __launch_bounds__(256) void fcos_match_kernel(
    const float* __restrict__ locations,      // (L,2)
    const float* __restrict__ strides_per_loc,// (L,)
    const float* __restrict__ soi,            // (L,2)
    const float* __restrict__ anchors,        // (L,4)
    const float* __restrict__ gt_boxes,       // (B,G,4)
    const int*   __restrict__ gt_classes,     // (B,G)
    float* __restrict__ out,                  // cls (B*L) | reg (B*L*4) | deltas (B*L*4)
    int L, int B)
{
    const int b = blockIdx.y;

    __shared__ float4 sbox[NGT];
    __shared__ float  sclsf[NGT];
    if (threadIdx.x < NGT) {
        const int j = threadIdx.x;
        sbox[j]  = reinterpret_cast<const float4*>(gt_boxes)[b * NGT + j];
        sclsf[j] = (float)gt_classes[b * NGT + j];
    }
    __syncthreads();

    // 2 threads per location: k = parity, each scans 32 boxes.
    const int  k      = threadIdx.x & 1;
    const int  p      = blockIdx.x * 128 + (threadIdx.x >> 1);
    const bool active = p < L;
    const int  i      = active ? p : 0;

    const float2 xy   = reinterpret_cast<const float2*>(locations)[i];
    const float  x    = xy.x, y = xy.y;
    const float  rad  = strides_per_loc[i] * RADIUS_F;
    const float2 lohi = reinterpret_cast<const float2*>(soi)[i];

    float minv = INF_F;
    int   ind  = k << 5;       // this thread's first global box index

    #pragma unroll
    for (int j = 0; j < 32; ++j) {
        const int jg = (k << 5) | j;
        const float4 bx = sbox[jg];         // 2-way multicast b128 (free)

        const float l = x - bx.x, t = y - bx.y;
        const float r = bx.z - x, d = bx.w - y;
        const float mx = fmaxf(fmaxf(fmaxf(l, t), r), d);   // max3+max
        const float mn = fminf(fminf(fminf(l, t), r), d);   // min3+min

        // bit-identical to staged ccx/ccy/area of R4 (validated absmax 0.0)
        const float ccx = (bx.x + bx.z) * 0.5f;
        const float ccy = (bx.y + bx.w) * 0.5f;
        const float cx  = rad - fabsf(x - ccx);
        const float cy  = rad - fabsf(y - ccy);
        const float cmin = fminf(fminf(mn, cx), cy);        // min3

        const float g    = fminf(mx - lohi.x, lohi.y - mx);
        const float area = (bx.z - bx.x) * (bx.w - bx.y);
        const float v = ((cmin > 0.0f) && (g >= 0.0f)) ? area : INF_F;
        if (v < minv) { minv = v; ind = jg; }  // strict < = first occurrence
    }

    // Pair-combine: lower-j half (k=0) wins ties -> exact first-occurrence argmin.
    const float vp   = __shfl_xor(minv, 1);
    const int   indp = __shfl_xor(ind, 1);
    const bool  take = (vp < minv) || ((vp == minv) && (k != 0));
    minv = take ? vp : minv;
    ind  = take ? indp : ind;

    if (!active) return;

    const float4 mb = sbox[ind];           // pair-shared divergent gather
    const size_t o4 = (size_t)b * L + i;

    if (k == 0) {
        // cls + reg targets
        out[o4] = (minv == INF_F) ? NUM_CLASSES_F : sclsf[ind];
        float4* reg4 = reinterpret_cast<float4*>(out + (size_t)B * L) + o4;
        *reg4 = make_float4(x - mb.x, y - mb.y, mb.z - x, mb.w - y);
    } else {
        // deltas (div/log heavy) on the odd lane
        const float4 an = reinterpret_cast<const float4*>(anchors)[i];
        const float aw  = an.z - an.x;
        const float ah  = an.w - an.y;
        const float acx = an.x + 0.5f * aw;
        const float acy = an.y + 0.5f * ah;
        const float gw  = mb.z - mb.x;
        const float gh  = mb.w - mb.y;
        const float gcx = mb.x + 0.5f * gw;
        const float gcy = mb.y + 0.5f * gh;

        float4* del4 = reinterpret_cast<float4*>(out + (size_t)B * L * 5) + o4;
        *del4 = make_float4((gcx - acx) / aw, (gcy - acy) / ah,
                            logf(gw / aw), logf(gh / ah));
    }
}

extern "C" void kernel_launch(void* const* d_in, const int* in_sizes, int n_in,
                              void* d_out, int out_size, void* d_ws, size_t ws_size,
                              hipStream_t stream) {
    const float* locations = (const float*)d_in[0];
    const float* strides   = (const float*)d_in[1];
    const float* soi       = (const float*)d_in[2];
    const float* anchors   = (const float*)d_in[3];
    const float* gt_boxes  = (const float*)d_in[4];
    const int*   gt_cls    = (const int*)d_in[5];
    float* out = (float*)d_out;

    const int L = in_sizes[1];            // strides_per_loc has L elements
    const int B = in_sizes[5] / NGT;      // gt_classes has B*G elements

    dim3 grid((L + 127) / 128, B);        // 128 locations per 256-thread block
    fcos_match_kernel<<<grid, dim3(256), 0, stream>>>(locations, strides, soi, anchors,
                                                      gt_boxes, gt_cls, out, L, B);
}